// Round 3
// baseline (186.835 us; speedup 1.0000x reference)
//
#include <hip/hip_runtime.h>
#include <math.h>

typedef __attribute__((ext_vector_type(4))) float f32x4;
typedef __attribute__((ext_vector_type(2))) float f32x2;
typedef __attribute__((ext_vector_type(8))) __bf16 bf16x8;
typedef __attribute__((ext_vector_type(4))) __bf16 bf16x4;
typedef __attribute__((ext_vector_type(2))) __bf16 bf16x2;

// ---------------- path tables (order matches Python PATHS enumeration) ----------
__device__ __constant__ int GP_L[34]  = {0,0,0,0, 1,1,1,1,1,1,1,1,1, 2,2,2,2,2,2,2,2,2,2,2, 3,3,3,3,3,3,3,3,3,3};
__device__ __constant__ int GP_L1[34] = {0,1,2,3, 0,1,1,1,2,2,2,3,3, 0,1,1,1,2,2,2,2,3,3,3, 0,1,1,2,2,2,3,3,3,3};
__device__ __constant__ int GP_L2[34] = {0,1,2,3, 1,0,1,2,1,2,3,2,3, 2,1,2,3,0,1,2,3,1,2,3, 3,2,3,1,2,3,0,1,2,3};

// ---------------- CG coefficient init (Racah formula, double) -------------------
__device__ double dfact(int n) { double r = 1.0; for (int i = 2; i <= n; ++i) r *= (double)i; return r; }

__device__ double cg_coeff(int l1, int m1, int l2, int m2, int l3, int m3) {
  if (m3 != m1 + m2) return 0.0;
  double pref = sqrt((2.0 * l3 + 1.0) * dfact(l3 + l1 - l2) * dfact(l3 - l1 + l2)
                     * dfact(l1 + l2 - l3) / dfact(l1 + l2 + l3 + 1));
  pref *= sqrt(dfact(l3 + m3) * dfact(l3 - m3) * dfact(l1 - m1) * dfact(l1 + m1)
               * dfact(l2 - m2) * dfact(l2 + m2));
  double s = 0.0;
  for (int k = 0; k <= l1 + l2 - l3; ++k) {
    int d0 = k, d1 = l1 + l2 - l3 - k, d2 = l1 - m1 - k, d3 = l2 + m2 - k;
    int d4 = l3 - l2 + m1 + k, d5 = l3 - l1 - m2 + k;
    if (d0 < 0 || d1 < 0 || d2 < 0 || d3 < 0 || d4 < 0 || d5 < 0) continue;
    double den = dfact(d0) * dfact(d1) * dfact(d2) * dfact(d3) * dfact(d4) * dfact(d5);
    s += ((k & 1) ? -1.0 : 1.0) / den;
  }
  return pref * s;
}

__global__ void cg_init(float* __restrict__ cg) {
  int idx = blockIdx.x * 256 + threadIdx.x;
  if (idx >= 34 * 49) return;
  int gp = idx / 49, r = idx % 49;
  int m1i = r / 7, m2i = r % 7;
  int l3 = GP_L[gp], l1 = GP_L1[gp], l2 = GP_L2[gp];
  float v = 0.f;
  if (m1i <= 2 * l1 && m2i <= 2 * l2) {
    int m1 = m1i - l1, m2 = m2i - l2, m3 = m1 + m2;
    if (m3 >= -l3 && m3 <= l3) v = (float)cg_coeff(l1, m1, l2, m2, l3, m3);
  }
  cg[idx] = v;
}

// ---------------- conversions ---------------------------------------------------
__global__ __launch_bounds__(256) void cvt_u_all(
    const float* __restrict__ u0, const float* __restrict__ u1,
    const float* __restrict__ u2, const float* __restrict__ u3,
    __bf16* __restrict__ out) {
  long i = (long)blockIdx.x * 256 + threadIdx.x;  // float4 index; grid sized exactly
  const long b1 = 65536, b2 = 212992, b3 = 393216;
  const float* src; long s;
  if (i < b1)      { src = u0; s = i; }
  else if (i < b2) { src = u1; s = i - b1; }
  else if (i < b3) { src = u2; s = i - b2; }
  else             { src = u3; s = i - b3; }
  float4 v = ((const float4*)src)[s];
  bf16x4 o;
  o[0] = (__bf16)v.x; o[1] = (__bf16)v.y; o[2] = (__bf16)v.z; o[3] = (__bf16)v.w;
  ((bf16x4*)out)[i] = o;
}

__global__ void wt_cvt_all(const float* __restrict__ w0, const float* __restrict__ w1,
                           const float* __restrict__ w2, const float* __restrict__ w3,
                           __bf16* __restrict__ Wt) {
  int b = blockIdx.x;            // l*256 + j
  int l = b >> 8, j = b & 255, k = threadIdx.x;
  const float* W = (l == 0) ? w0 : (l == 1) ? w1 : (l == 2) ? w2 : w3;
  Wt[((long)l << 16) + (j << 8) + k] = (__bf16)W[(k << 8) + j];
}

// ---------------- batched bf16 MFMA GEMM (UW precompute only) -------------------
struct GemmDesc {
  const __bf16* A[4];
  const __bf16* B[4];
  void*         C[4];
  const float*  R[4];
  int start[4];
  int lmap[4];
  int Kd[4];
  int Nc[4];
};

__device__ __forceinline__ void gload_lds16(const void* g, void* l) {
  __builtin_amdgcn_global_load_lds((const __attribute__((address_space(1))) void*)g,
                                   (__attribute__((address_space(3))) void*)l, 16, 0, 0);
}

template <bool OUT_BF16, bool RESID>
__global__ __launch_bounds__(256) void gemm_batched(GemmDesc d) {
  __shared__ __bf16 As[128 * 64];
  __shared__ __bf16 Bs[128 * 64];
  const int tid = threadIdx.x;
  const int bid = blockIdx.x;
  int seg = 0;
  if (bid >= d.start[1]) seg = 1;
  if (bid >= d.start[2]) seg = 2;
  if (bid >= d.start[3]) seg = 3;
  const int l = d.lmap[seg];
  const int rel = bid - d.start[seg];
  const int Kd = d.Kd[l], Nc = d.Nc[l];
  const int nTN = Nc >> 7;
  const int tM = rel / nTN, tN = rel % nTN;

  const int lane = tid & 63, wave = tid >> 6;
  const int wm = (wave >> 1) << 6, wn = (wave & 1) << 6;
  const int lr = lane & 15, lk = (lane >> 4) << 3;

  f32x4 acc[4][4] = {};

  const int r32 = tid >> 3;
  const int sl = ((tid & 7) ^ (r32 & 7)) << 3;
  const __bf16* Ag = d.A[l] + (long)(tM * 128 + r32) * Kd + sl;
  const __bf16* Bg = d.B[l] + (long)(tN * 128 + r32) * Kd + sl;
  char* AsB = (char*)As;
  char* BsB = (char*)Bs;

  for (int kt = 0; kt < Kd; kt += 64) {
#pragma unroll
    for (int i = 0; i < 4; ++i) {
      gload_lds16(Ag + (long)i * 32 * Kd + kt, AsB + i * 4096 + tid * 16);
      gload_lds16(Bg + (long)i * 32 * Kd + kt, BsB + i * 4096 + tid * 16);
    }
    __syncthreads();

#pragma unroll
    for (int kk = 0; kk < 64; kk += 32) {
      bf16x8 af[4], bfr[4];
#pragma unroll
      for (int mi = 0; mi < 4; ++mi)
        af[mi] = *(const bf16x8*)(AsB + ((wm + mi * 16 + lr) << 7)
                                      + ((((kk + lk) << 1)) ^ ((lr & 7) << 4)));
#pragma unroll
      for (int ni = 0; ni < 4; ++ni)
        bfr[ni] = *(const bf16x8*)(BsB + ((wn + ni * 16 + lr) << 7)
                                       + ((((kk + lk) << 1)) ^ ((lr & 7) << 4)));
#pragma unroll
      for (int mi = 0; mi < 4; ++mi)
#pragma unroll
        for (int ni = 0; ni < 4; ++ni)
          acc[mi][ni] = __builtin_amdgcn_mfma_f32_16x16x32_bf16(af[mi], bfr[ni], acc[mi][ni], 0, 0, 0);
    }
    __syncthreads();
  }

  const long col0 = (long)tN * 128 + wn + lr;
  const long row0 = (long)tM * 128 + wm + ((lane >> 4) << 2);
#pragma unroll
  for (int mi = 0; mi < 4; ++mi) {
#pragma unroll
    for (int j = 0; j < 4; ++j) {
      long r = row0 + mi * 16 + j;
      long base = r * (long)Nc + col0;
#pragma unroll
      for (int ni = 0; ni < 4; ++ni) {
        long idx = base + ni * 16;
        float v = acc[mi][ni][j];
        if constexpr (RESID) v += d.R[l][idx];
        if constexpr (OUT_BF16) ((__bf16*)d.C[l])[idx] = (__bf16)v;
        else                    ((float*)d.C[l])[idx] = v;
      }
    }
  }
}

// ---------------- fused TP + GEMM -----------------------------------------------
// Per block: TROWS x 256 output tile. Per K-step (BK=64, one path):
//   stage B (UWt) via global_load_lds; compute TP A-tile in registers and
//   ds_write (XOR-swizzled); barrier; ds_read frags + MFMA; barrier.
struct FusedArgs {
  const float* f1[4];
  const float* f2[4];
  const float* cg;
  const __bf16* UWt;
  float* out;
};

template <int L, int L1V, int L2V>
__device__ __forceinline__ void tp_pass(
    const float* __restrict__ f1, const float* __restrict__ f2,
    long n, int kc, int k2, const float* __restrict__ cgt,
    char* __restrict__ AsB, int row0) {
  f32x2 v1[2 * L1V + 1], v2[2 * L2V + 1];
  const float* p1 = f1 + (n * (2 * L1V + 1)) * 256 + kc + k2;
  const float* p2 = f2 + (n * (2 * L2V + 1)) * 256 + kc + k2;
#pragma unroll
  for (int a = 0; a < 2 * L1V + 1; ++a) v1[a] = *(const f32x2*)(p1 + a * 256);
#pragma unroll
  for (int b = 0; b < 2 * L2V + 1; ++b) v2[b] = *(const f32x2*)(p2 + b * 256);
  f32x2 tp[2 * L + 1];
#pragma unroll
  for (int m = 0; m < 2 * L + 1; ++m) { tp[m][0] = 0.f; tp[m][1] = 0.f; }
#pragma unroll
  for (int a = 0; a < 2 * L1V + 1; ++a)
#pragma unroll
    for (int b = 0; b < 2 * L2V + 1; ++b) {
      const int m = a + b - (L1V + L2V - L);   // constant after unroll
      if (m >= 0 && m <= 2 * L) {
        float c = cgt[a * 7 + b];
        tp[m][0] = fmaf(c, v1[a][0] * v2[b][0], tp[m][0]);
        tp[m][1] = fmaf(c, v1[a][1] * v2[b][1], tp[m][1]);
      }
    }
#pragma unroll
  for (int m = 0; m < 2 * L + 1; ++m) {
    int row = row0 + m;
    int byte = row * 128 + ((k2 << 1) ^ ((row & 7) << 4));
    bf16x2 o; o[0] = (__bf16)tp[m][0]; o[1] = (__bf16)tp[m][1];
    *(bf16x2*)(AsB + byte) = o;
  }
}

#define TPC(P, AA, BB)                                                          \
  case P: {                                                                     \
    _Pragma("unroll")                                                           \
    for (int ps = 0; ps < NPASS; ++ps)                                          \
      tp_pass<L, AA, BB>(Af.f1[AA], Af.f2[BB], n0 + ps * 8 + nloc, kc, k2,      \
                         cgb + (GOFF + P) * 49, AsB, (ps * 8 + nloc) * (2 * L + 1)); \
  } break;

template <int L>
__device__ __forceinline__ void fused_seg(
    const FusedArgs& Af, int rel, char* __restrict__ AsB, char* __restrict__ BsB,
    const __bf16* __restrict__ Bmat, float* __restrict__ Cout,
    const float* __restrict__ Resid, int cin) {
  constexpr int NB    = (L == 0) ? 64 : (L == 1) ? 16 : 8;   // n-values per block
  constexpr int TROWS = (L == 0 || L == 3) ? 64 : 48;        // LDS tile rows
  constexpr int VALID = NB * (2 * L + 1);                    // real rows
  constexpr int MR    = TROWS / 16;
  constexpr int NPASS = NB / 8;
  constexpr int GOFF  = (L == 0) ? 0 : (L == 1) ? 4 : (L == 2) ? 13 : 24;

  const int tid = threadIdx.x;
  const int lane = tid & 63, wave = tid >> 6;
  const long n0 = (long)rel * NB;
  const int nloc = tid >> 5;          // 0..7 (n within pass)
  const int k2 = (tid & 31) << 1;     // even k; thread owns k2, k2+1
  const float* cgb = Af.cg;

  if constexpr (VALID < TROWS) {      // zero pad rows once; stay zero all K-steps
    if (tid < (TROWS - VALID) * 8) {
      f32x4 z = {0.f, 0.f, 0.f, 0.f};
      *(f32x4*)(AsB + (VALID + (tid >> 3)) * 128 + (tid & 7) * 16) = z;
    }
  }

  f32x4 acc[MR][4];
#pragma unroll
  for (int i = 0; i < MR; ++i)
#pragma unroll
    for (int j = 0; j < 4; ++j) acc[i][j] = {0.f, 0.f, 0.f, 0.f};

  const __bf16* Bg = Bmat + (long)(tid >> 3) * cin + (((tid & 7) ^ ((tid >> 3) & 7)) << 3);

  for (int kt = 0; kt < cin; kt += 64) {
#pragma unroll
    for (int i = 0; i < 8; ++i)
      gload_lds16(Bg + (long)i * 32 * cin + kt, BsB + i * 4096 + tid * 16);

    const int p = kt >> 8, kc = kt & 255;
    if constexpr (L == 0) {
      switch (p) { TPC(0,0,0) TPC(1,1,1) TPC(2,2,2) TPC(3,3,3) default: break; }
    } else if constexpr (L == 1) {
      switch (p) { TPC(0,0,1) TPC(1,1,0) TPC(2,1,1) TPC(3,1,2) TPC(4,2,1)
                   TPC(5,2,2) TPC(6,2,3) TPC(7,3,2) TPC(8,3,3) default: break; }
    } else if constexpr (L == 2) {
      switch (p) { TPC(0,0,2) TPC(1,1,1) TPC(2,1,2) TPC(3,1,3) TPC(4,2,0)
                   TPC(5,2,1) TPC(6,2,2) TPC(7,2,3) TPC(8,3,1) TPC(9,3,2)
                   TPC(10,3,3) default: break; }
    } else {
      switch (p) { TPC(0,0,3) TPC(1,1,2) TPC(2,1,3) TPC(3,2,1) TPC(4,2,2)
                   TPC(5,2,3) TPC(6,3,0) TPC(7,3,1) TPC(8,3,2) TPC(9,3,3)
                   default: break; }
    }

    __syncthreads();

#pragma unroll
    for (int kk = 0; kk < 64; kk += 32) {
      const int kb = ((kk + ((lane >> 4) << 3)) << 1) ^ ((lane & 7) << 4);
      bf16x8 af[MR], bfr[4];
#pragma unroll
      for (int mi = 0; mi < MR; ++mi)
        af[mi] = *(const bf16x8*)(AsB + (mi * 16 + (lane & 15)) * 128 + kb);
#pragma unroll
      for (int ni = 0; ni < 4; ++ni)
        bfr[ni] = *(const bf16x8*)(BsB + ((wave << 6) + ni * 16 + (lane & 15)) * 128 + kb);
#pragma unroll
      for (int mi = 0; mi < MR; ++mi)
#pragma unroll
        for (int ni = 0; ni < 4; ++ni)
          acc[mi][ni] = __builtin_amdgcn_mfma_f32_16x16x32_bf16(af[mi], bfr[ni], acc[mi][ni], 0, 0, 0);
    }
    __syncthreads();
  }

  const int col = (wave << 6) + (lane & 15);
  const int rb = (lane >> 4) << 2;
#pragma unroll
  for (int mi = 0; mi < MR; ++mi)
#pragma unroll
    for (int j = 0; j < 4; ++j) {
      int r = mi * 16 + rb + j;
      if (VALID < TROWS && r >= VALID) continue;
      long idx = ((long)rel * VALID + r) * 256 + col;
#pragma unroll
      for (int ni = 0; ni < 4; ++ni)
        Cout[idx + ni * 16] = acc[mi][ni][j] + Resid[idx + ni * 16];
    }
}

__global__ __launch_bounds__(256, 2) void fused_kernel(FusedArgs Af) {
  __shared__ __align__(16) char sm[8192 + 32768];
  char* AsB = sm;
  char* BsB = sm + 8192;
  const int bid = blockIdx.x;
  // segment order: l2 (256), l3 (256), l1 (128), l0 (32)
  if (bid < 256) {
    fused_seg<2>(Af, bid, AsB, BsB, Af.UWt + 3328L * 256, Af.out + 2097152L, Af.f1[2], 2816);
  } else if (bid < 512) {
    fused_seg<3>(Af, bid - 256, AsB, BsB, Af.UWt + 6144L * 256, Af.out + 4718592L, Af.f1[3], 2560);
  } else if (bid < 640) {
    fused_seg<1>(Af, bid - 512, AsB, BsB, Af.UWt + 1024L * 256, Af.out + 524288L, Af.f1[1], 2304);
  } else {
    fused_seg<0>(Af, bid - 640, AsB, BsB, Af.UWt, Af.out, Af.f1[0], 1024);
  }
}

// ---------------- launch ---------------------------------------------------------
extern "C" void kernel_launch(void* const* d_in, const int* in_sizes, int n_in,
                              void* d_out, int out_size, void* d_ws, size_t ws_size,
                              hipStream_t stream) {
  const float* F1[4], * F2[4], * Uin[4], * Win[4];
  for (int l = 0; l < 4; ++l) {
    F1[l]  = (const float*)d_in[4 * l + 0];
    F2[l]  = (const float*)d_in[4 * l + 1];
    Uin[l] = (const float*)d_in[4 * l + 2];
    Win[l] = (const float*)d_in[4 * l + 3];
  }
  static const int cin_[4] = {1024, 2304, 2816, 2560};
  static const int cum_[4] = {0, 1024, 3328, 6144};

  char* ws = (char*)d_ws;
  float*  cg   = (float*)ws;                        // 6664 B
  __bf16* Ubf  = (__bf16*)(ws + 8192);              // 4,456,448 B
  __bf16* Wtbf = (__bf16*)(ws + 8192 + 4456448);    // 524,288 B
  __bf16* UWt  = (__bf16*)(ws + 5242880);           // 4,456,448 B

  hipLaunchKernelGGL(cg_init, dim3(7), dim3(256), 0, stream, cg);
  hipLaunchKernelGGL(cvt_u_all, dim3(2176), dim3(256), 0, stream,
                     Uin[0], Uin[1], Uin[2], Uin[3], Ubf);
  hipLaunchKernelGGL(wt_cvt_all, dim3(1024), dim3(256), 0, stream,
                     Win[0], Win[1], Win[2], Win[3], Wtbf);

  // UWt_l[j][c] = sum_k W_l[k][j] * U_l[c][k]; one batched launch.
  {
    GemmDesc d;
    int starts[4] = {0, 40, 84, 120};  // order l3,l2,l1,l0
    int lmap[4]   = {3, 2, 1, 0};
    for (int s = 0; s < 4; ++s) { d.start[s] = starts[s]; d.lmap[s] = lmap[s]; }
    for (int l = 0; l < 4; ++l) {
      d.A[l] = Wtbf + (long)l * 65536;
      d.B[l] = Ubf + (long)cum_[l] * 256;
      d.C[l] = (void*)(UWt + (long)cum_[l] * 256);
      d.R[l] = nullptr;
      d.Kd[l] = 256;
      d.Nc[l] = cin_[l];
    }
    hipLaunchKernelGGL((gemm_batched<true, false>), dim3(136), dim3(256), 0, stream, d);
  }

  // fused TP + main GEMM + residual, one launch
  {
    FusedArgs a;
    for (int l = 0; l < 4; ++l) { a.f1[l] = F1[l]; a.f2[l] = F2[l]; }
    a.cg = cg;
    a.UWt = UWt;
    a.out = (float*)d_out;
    hipLaunchKernelGGL(fused_kernel, dim3(672), dim3(256), 0, stream, a);
  }
  (void)in_sizes; (void)n_in; (void)out_size; (void)ws_size;
}